// Round 17
// baseline (404.672 us; speedup 1.0000x reference)
//
#include <hip/hip_runtime.h>

// Fused KernelWarehouse dynamic conv, round 14 (base plateau: 82us, R10/R15):
//   logits = 1x1 conv -> softmax K=4 -> 3x3 convs -> mixture (dot2 f16 path).
// R5-R16 falsified: TLP, barrier semantics/count, LDS width, fetch volume,
// iteration count, burst length. All kept the {stage->barrier->compute}
// skeleton. R17: ZERO-LDS ZERO-BARRIER register pipeline. One wave = one
// full image row (64 lanes x 4 px): horizontal halo = __shfl_up/down with
// lane 0/63 edge = the zero-pad itself. Per channel pair a wave loads rows
// h-1,h,h+1 (3 coalesced 1KB runs x 2 planes), packs to half2, computes.
// Vertical 3x re-read is L2-absorbed: rows [512x, 512x+512) pinned to XCD x
// (fid&7 = XCD under round-robin), all 512 waves/XCD co-resident convoy
// through channels (~1MB/XCD working set per pair << 4MB L2).
// Kept: dot2/half2 channel pairs, packed weights in d_ws, 2-deep register
// prefetch, f32 epilogue.

typedef _Float16 half2_t __attribute__((ext_vector_type(2)));
typedef unsigned int uint;

#define HH 256
#define WW 256
#define CH 64
#define PLANE (HH * WW)
#define NG 32                    // channel pairs
// packed-weight table in d_ws:
//   uint wpk[4][32][9] : half2(w[k][2p][tap], w[k][2p+1][tap])  (1152)
//   uint apk[4][32]    : half2(attn_w[k][2p], attn_w[k][2p+1])  (128)
#define WPK_N 1152
#define APK_OFF 1152

__device__ __forceinline__ uint pkrtz(float a, float b) {
    return __builtin_bit_cast(uint, __builtin_amdgcn_cvt_pkrtz(a, b));
}

__device__ __forceinline__ float dot2(uint a, uint b, float c) {
#if __has_builtin(__builtin_amdgcn_fdot2)
    return __builtin_amdgcn_fdot2(__builtin_bit_cast(half2_t, a),
                                  __builtin_bit_cast(half2_t, b), c, false);
#else
    half2_t ha = __builtin_bit_cast(half2_t, a);
    half2_t hb = __builtin_bit_cast(half2_t, b);
    return c + (float)ha[0] * (float)hb[0] + (float)ha[1] * (float)hb[1];
#endif
}

__global__ void kwdc_pack(const float* __restrict__ weight,
                          const float* __restrict__ attn_w,
                          uint* __restrict__ wsu) {
    int e = blockIdx.x * 256 + threadIdx.x;
    if (e < WPK_N) {
        int k = e / 288, rem = e % 288, pair = rem / 9, tap = rem % 9;
        int c0 = 2 * pair;
        wsu[e] = pkrtz(weight[(k * CH + c0) * 9 + tap],
                       weight[(k * CH + c0 + 1) * 9 + tap]);
    } else if (e < WPK_N + 128) {
        int e2 = e - WPK_N;
        int k = e2 / 32, pair = e2 % 32;
        int c0 = 2 * pair;
        wsu[APK_OFF + e2] = pkrtz(attn_w[k * CH + c0], attn_w[k * CH + c0 + 1]);
    }
}

__global__ __launch_bounds__(256, 4) void kwdc_main(
    const float* __restrict__ x,       // [B,C,H,W] f32
    const uint*  __restrict__ wsu,     // packed weights (d_ws)
    const float* __restrict__ attn_b,  // [K] f32
    float* __restrict__ out)           // [B,1,H,W] f32
{
    const int lane = threadIdx.x & 63;
    const int wid  = threadIdx.x >> 6;          // wave in block (0..3)

    // rows [512*x, 512*x+512) -> blocks with fid&7==x (round-robin XCD x)
    const int fid = blockIdx.x;                 // 0..1023
    const int R   = (fid & 7) * 512 + (fid >> 3) * 4 + wid;  // global row 0..4095
    const int b   = R >> 8;                     // image
    const int h   = R & 255;                    // row in image

    const float* xb = x + (size_t)b * CH * PLANE;
    const int wb = lane * 4;                    // this lane's col base

    const bool topok = (h > 0);
    const bool botok = (h < HH - 1);
    const int  rbase = h * WW + wb;             // own-row offset within plane

    struct Set { float4 v[6]; };                // rows{-1,0,+1} x ch{a,b}
    Set sA, sB;

    auto load_set = [&](int g, Set& s) {
        const float* pa = xb + (size_t)(2 * g) * PLANE + rbase;   // ch a, row h
        const float* pb = pa + PLANE;                              // ch b
        float4 z = {0.f, 0.f, 0.f, 0.f};
        s.v[0] = topok ? *reinterpret_cast<const float4*>(pa - WW) : z;
        s.v[1] =         *reinterpret_cast<const float4*>(pa);
        s.v[2] = botok ? *reinterpret_cast<const float4*>(pa + WW) : z;
        s.v[3] = topok ? *reinterpret_cast<const float4*>(pb - WW) : z;
        s.v[4] =         *reinterpret_cast<const float4*>(pb);
        s.v[5] = botok ? *reinterpret_cast<const float4*>(pb + WW) : z;
    };

    float conv[4][4];
    float logit[4][4];
#pragma unroll
    for (int k = 0; k < 4; ++k)
#pragma unroll
        for (int p = 0; p < 4; ++p) { conv[k][p] = 0.f; logit[k][p] = 0.f; }

    load_set(0, sA);
    load_set(1, sB);

    for (int g = 0; g < NG; ++g) {
        Set& s = (g & 1) ? sB : sA;

        // ---- pack own 4 px per row into ch-pair half2 ----
        uint own[3][4];
#pragma unroll
        for (int i = 0; i < 3; ++i) {
            const float4& a4 = s.v[i];       // ch a, row i
            const float4& b4 = s.v[i + 3];   // ch b, row i
            own[i][0] = pkrtz(a4.x, b4.x);
            own[i][1] = pkrtz(a4.y, b4.y);
            own[i][2] = pkrtz(a4.z, b4.z);
            own[i][3] = pkrtz(a4.w, b4.w);
        }

        // ---- refill this set with group g+2 (2-deep prefetch) ----
        if (g + 2 < NG) load_set(g + 2, s);

        // ---- horizontal halo via cross-lane; lane 0/63 = image zero-pad ----
        uint rv[3][6];
#pragma unroll
        for (int i = 0; i < 3; ++i) {
            uint L  = (uint)__shfl_up((int)own[i][3], 1);
            uint Rt = (uint)__shfl_down((int)own[i][0], 1);
            rv[i][0] = (lane == 0)  ? 0u : L;
            rv[i][1] = own[i][0]; rv[i][2] = own[i][1];
            rv[i][3] = own[i][2]; rv[i][4] = own[i][3];
            rv[i][5] = (lane == 63) ? 0u : Rt;
        }

        // ---- packed weights for this pair (uniform -> s_load) ----
        uint w2[4][9];
        uint a2[4];
#pragma unroll
        for (int k = 0; k < 4; ++k) {
            const uint* wq = wsu + k * 288 + g * 9;
#pragma unroll
            for (int t = 0; t < 9; ++t) w2[k][t] = wq[t];
            a2[k] = wsu[APK_OFF + k * 32 + g];
        }

        // ---- compute both channels of the pair via dot2 ----
#pragma unroll
        for (int k = 0; k < 4; ++k) {
#pragma unroll
            for (int p = 0; p < 4; ++p) {
                float acc = conv[k][p];
                acc = dot2(rv[0][p],     w2[k][0], acc);
                acc = dot2(rv[0][p + 1], w2[k][1], acc);
                acc = dot2(rv[0][p + 2], w2[k][2], acc);
                acc = dot2(rv[1][p],     w2[k][3], acc);
                acc = dot2(rv[1][p + 1], w2[k][4], acc);
                acc = dot2(rv[1][p + 2], w2[k][5], acc);
                acc = dot2(rv[2][p],     w2[k][6], acc);
                acc = dot2(rv[2][p + 1], w2[k][7], acc);
                acc = dot2(rv[2][p + 2], w2[k][8], acc);
                conv[k][p] = acc;
                logit[k][p] = dot2(rv[1][p + 1], a2[k], logit[k][p]);
            }
        }
        // no LDS, no barrier: next iteration's pack waits (per-register
        // vmcnt) only on loads issued 2 iterations ago.
    }

    // ---- epilogue: softmax over K=4 + mixture (all f32) ----
    const float b0 = attn_b[0], b1 = attn_b[1], b2 = attn_b[2], b3 = attn_b[3];
    float4 o;
    float* op = &o.x;
#pragma unroll
    for (int p = 0; p < 4; ++p) {
        float l0 = logit[0][p] + b0;
        float l1 = logit[1][p] + b1;
        float l2 = logit[2][p] + b2;
        float l3 = logit[3][p] + b3;
        float m = fmaxf(fmaxf(l0, l1), fmaxf(l2, l3));
        float e0 = __expf(l0 - m), e1 = __expf(l1 - m);
        float e2 = __expf(l2 - m), e3 = __expf(l3 - m);
        float sden = e0 + e1 + e2 + e3;
        float num = conv[0][p] * e0 + conv[1][p] * e1
                  + conv[2][p] * e2 + conv[3][p] * e3;
        op[p] = num / sden;
    }
    size_t oidx = (size_t)b * PLANE + (size_t)h * WW + wb;
    *reinterpret_cast<float4*>(out + oidx) = o;
}

extern "C" void kernel_launch(void* const* d_in, const int* in_sizes, int n_in,
                              void* d_out, int out_size, void* d_ws, size_t ws_size,
                              hipStream_t stream) {
    const float* x      = (const float*)d_in[0];
    const float* weight = (const float*)d_in[1];
    const float* attn_w = (const float*)d_in[2];
    const float* attn_b = (const float*)d_in[3];
    float* out = (float*)d_out;
    uint*  wsu = (uint*)d_ws;

    kwdc_pack<<<dim3(5), 256, 0, stream>>>(weight, attn_w, wsu);
    kwdc_main<<<dim3(1024), 256, 0, stream>>>(x, wsu, attn_b, out);
}

// Round 18
// 134.668 us; speedup vs baseline: 3.0050x; 3.0050x over previous
//
#include <hip/hip_runtime.h>

// Fused KernelWarehouse dynamic conv, round 15 (R17 scratch-bug fix):
//   logits = 1x1 conv -> softmax K=4 -> 3x3 convs -> mixture (dot2 f16 path).
// R17's zero-LDS zero-barrier register pipeline was sabotaged by rule #20:
// `Set& s = (g&1) ? sB : sA` in a runtime loop -> both sets in SCRATCH
// (WRITE_SIZE 910 MB, VGPR 40, 404us). R18: manual unroll-by-2 with an
// inlined body taking a compile-time-distinct Set& -> all accesses
// statically indexed, sets live in VGPRs.
// Structure: one wave = one image row (64 lanes x 4px); horizontal halo via
// __shfl, lane 0/63 edge = zero-pad; per pair load rows h-1,h,h+1 x 2 planes
// (6 x 1KB coalesced runs); vertical 3x re-read L2-absorbed (rows [512x,
// 512x+512) pinned to XCD x). No LDS, no barriers, per-register vmcnt only.

typedef _Float16 half2_t __attribute__((ext_vector_type(2)));
typedef unsigned int uint;

#define HH 256
#define WW 256
#define CH 64
#define PLANE (HH * WW)
#define NG 32                    // channel pairs
#define WPK_N 1152
#define APK_OFF 1152

__device__ __forceinline__ uint pkrtz(float a, float b) {
    return __builtin_bit_cast(uint, __builtin_amdgcn_cvt_pkrtz(a, b));
}

__device__ __forceinline__ float dot2(uint a, uint b, float c) {
#if __has_builtin(__builtin_amdgcn_fdot2)
    return __builtin_amdgcn_fdot2(__builtin_bit_cast(half2_t, a),
                                  __builtin_bit_cast(half2_t, b), c, false);
#else
    half2_t ha = __builtin_bit_cast(half2_t, a);
    half2_t hb = __builtin_bit_cast(half2_t, b);
    return c + (float)ha[0] * (float)hb[0] + (float)ha[1] * (float)hb[1];
#endif
}

__global__ void kwdc_pack(const float* __restrict__ weight,
                          const float* __restrict__ attn_w,
                          uint* __restrict__ wsu) {
    int e = blockIdx.x * 256 + threadIdx.x;
    if (e < WPK_N) {
        int k = e / 288, rem = e % 288, pair = rem / 9, tap = rem % 9;
        int c0 = 2 * pair;
        wsu[e] = pkrtz(weight[(k * CH + c0) * 9 + tap],
                       weight[(k * CH + c0 + 1) * 9 + tap]);
    } else if (e < WPK_N + 128) {
        int e2 = e - WPK_N;
        int k = e2 / 32, pair = e2 % 32;
        int c0 = 2 * pair;
        wsu[APK_OFF + e2] = pkrtz(attn_w[k * CH + c0], attn_w[k * CH + c0 + 1]);
    }
}

struct Set { float4 v[6]; };   // rows{-1,0,+1} x ch{a,b}

__global__ __launch_bounds__(256) void kwdc_main(
    const float* __restrict__ x,       // [B,C,H,W] f32
    const uint*  __restrict__ wsu,     // packed weights (d_ws)
    const float* __restrict__ attn_b,  // [K] f32
    float* __restrict__ out)           // [B,1,H,W] f32
{
    const int lane = threadIdx.x & 63;
    const int wid  = threadIdx.x >> 6;          // wave in block (0..3)

    // rows [512*x, 512*x+512) -> blocks with fid&7==x (round-robin XCD x)
    const int fid = blockIdx.x;                 // 0..1023
    const int R   = (fid & 7) * 512 + (fid >> 3) * 4 + wid;  // global row
    const int b   = R >> 8;                     // image
    const int h   = R & 255;                    // row in image

    const float* xb = x + (size_t)b * CH * PLANE;
    const int wb = lane * 4;                    // this lane's col base

    const bool topok = (h > 0);
    const bool botok = (h < HH - 1);
    const int  rbase = h * WW + wb;

    float conv[4][4];
    float logit[4][4];
#pragma unroll
    for (int k = 0; k < 4; ++k)
#pragma unroll
        for (int p = 0; p < 4; ++p) { conv[k][p] = 0.f; logit[k][p] = 0.f; }

    auto load_set = [&](int g, Set& s) {
        const float* pa = xb + (size_t)(2 * g) * PLANE + rbase;   // ch a
        const float* pb = pa + PLANE;                              // ch b
        float4 z = {0.f, 0.f, 0.f, 0.f};
        s.v[0] = topok ? *reinterpret_cast<const float4*>(pa - WW) : z;
        s.v[1] =         *reinterpret_cast<const float4*>(pa);
        s.v[2] = botok ? *reinterpret_cast<const float4*>(pa + WW) : z;
        s.v[3] = topok ? *reinterpret_cast<const float4*>(pb - WW) : z;
        s.v[4] =         *reinterpret_cast<const float4*>(pb);
        s.v[5] = botok ? *reinterpret_cast<const float4*>(pb + WW) : z;
    };

    // body(g, s): consume s (group g), then refill s with group g+2.
    auto body = [&](int g, Set& s) {
        // pack own 4 px per row into ch-pair half2
        uint own[3][4];
#pragma unroll
        for (int i = 0; i < 3; ++i) {
            const float4& a4 = s.v[i];
            const float4& b4 = s.v[i + 3];
            own[i][0] = pkrtz(a4.x, b4.x);
            own[i][1] = pkrtz(a4.y, b4.y);
            own[i][2] = pkrtz(a4.z, b4.z);
            own[i][3] = pkrtz(a4.w, b4.w);
        }

        // refill (2-deep prefetch; issues before compute consumes VALU)
        if (g + 2 < NG) load_set(g + 2, s);

        // horizontal halo via cross-lane; lane 0/63 = image zero-pad
        uint rv[3][6];
#pragma unroll
        for (int i = 0; i < 3; ++i) {
            uint L  = (uint)__shfl_up((int)own[i][3], 1);
            uint Rt = (uint)__shfl_down((int)own[i][0], 1);
            rv[i][0] = (lane == 0)  ? 0u : L;
            rv[i][1] = own[i][0]; rv[i][2] = own[i][1];
            rv[i][3] = own[i][2]; rv[i][4] = own[i][3];
            rv[i][5] = (lane == 63) ? 0u : Rt;
        }

        // packed weights for this pair (uniform -> s_load)
#pragma unroll
        for (int k = 0; k < 4; ++k) {
            const uint* wq = wsu + k * 288 + g * 9;
            uint w2[9];
#pragma unroll
            for (int t = 0; t < 9; ++t) w2[t] = wq[t];
            const uint a2 = wsu[APK_OFF + k * 32 + g];
#pragma unroll
            for (int p = 0; p < 4; ++p) {
                float acc = conv[k][p];
                acc = dot2(rv[0][p],     w2[0], acc);
                acc = dot2(rv[0][p + 1], w2[1], acc);
                acc = dot2(rv[0][p + 2], w2[2], acc);
                acc = dot2(rv[1][p],     w2[3], acc);
                acc = dot2(rv[1][p + 1], w2[4], acc);
                acc = dot2(rv[1][p + 2], w2[5], acc);
                acc = dot2(rv[2][p],     w2[6], acc);
                acc = dot2(rv[2][p + 1], w2[7], acc);
                acc = dot2(rv[2][p + 2], w2[8], acc);
                conv[k][p] = acc;
                logit[k][p] = dot2(rv[1][p + 1], a2, logit[k][p]);
            }
        }
    };

    Set sA, sB;
    load_set(0, sA);
    load_set(1, sB);

    // manual unroll-by-2: sA/sB are compile-time-distinct lvalues -> no
    // runtime indexing -> sets stay in VGPRs (rule #20 fix for R17).
    for (int gg = 0; gg < NG; gg += 2) {
        body(gg,     sA);
        body(gg + 1, sB);
    }

    // ---- epilogue: softmax over K=4 + mixture (all f32) ----
    const float b0 = attn_b[0], b1 = attn_b[1], b2 = attn_b[2], b3 = attn_b[3];
    float4 o;
    float* op = &o.x;
#pragma unroll
    for (int p = 0; p < 4; ++p) {
        float l0 = logit[0][p] + b0;
        float l1 = logit[1][p] + b1;
        float l2 = logit[2][p] + b2;
        float l3 = logit[3][p] + b3;
        float m = fmaxf(fmaxf(l0, l1), fmaxf(l2, l3));
        float e0 = __expf(l0 - m), e1 = __expf(l1 - m);
        float e2 = __expf(l2 - m), e3 = __expf(l3 - m);
        float sden = e0 + e1 + e2 + e3;
        float num = conv[0][p] * e0 + conv[1][p] * e1
                  + conv[2][p] * e2 + conv[3][p] * e3;
        op[p] = num / sden;
    }
    size_t oidx = (size_t)b * PLANE + (size_t)h * WW + wb;
    *reinterpret_cast<float4*>(out + oidx) = o;
}

extern "C" void kernel_launch(void* const* d_in, const int* in_sizes, int n_in,
                              void* d_out, int out_size, void* d_ws, size_t ws_size,
                              hipStream_t stream) {
    const float* x      = (const float*)d_in[0];
    const float* weight = (const float*)d_in[1];
    const float* attn_w = (const float*)d_in[2];
    const float* attn_b = (const float*)d_in[3];
    float* out = (float*)d_out;
    uint*  wsu = (uint*)d_ws;

    kwdc_pack<<<dim3(5), 256, 0, stream>>>(weight, attn_w, wsu);
    kwdc_main<<<dim3(1024), 256, 0, stream>>>(x, wsu, attn_b, out);
}

// Round 19
// 82.057 us; speedup vs baseline: 4.9316x; 1.6411x over previous
//
#include <hip/hip_runtime.h>

// Fused KernelWarehouse dynamic conv — FINAL (R15 restore, benched 81.9us):
//   logits = 1x1 conv -> softmax K=4 -> 3x3 convs -> mixture (dot2 f16 path).
// Structure: 32x32 tiles (1024 blocks, XCD-swizzled so row-mates share an
// XCD L2), 256 thr, CPB=4 channels (2 half2 pairs) per group -> 16 iters,
// LDS double-buffer + 1 barrier/group, 2-deep register prefetch (store at
// iter g writes data loaded at g-2), v_dot2_f32_f16 with packed weights
// pre-built in d_ws, f32 softmax epilogue.
// Roofline note: 357 MB effective fetch at the ~4.35 TB/s this halo-tiled
// access shape sustains = ~82us. Ten structural variants (TLP, barrier
// semantics/count/existence, LDS width, fetch volume, burst length,
// zero-LDS register pipeline) all landed >=82us — this is the plateau.

typedef _Float16 half2_t __attribute__((ext_vector_type(2)));
typedef unsigned int uint;

#define HH 256
#define WW 256
#define CH 64
#define PLANE (HH * WW)
#define TILE 32
#define PAIRS 2                  // channel pairs per group
#define NG 16                    // groups (4 channels each)
#define ROWS 34                  // tile rows incl. halo
#define NC4 10                   // 4-dword units per row ([w0-4, w0+36))
#define LDSS 41                  // dword row stride (odd -> <=2-way read banks)
#define PSTRIDE (ROWS * LDSS)    // 1394 dwords per pair-plane
#define BUF_DW (PAIRS * PSTRIDE) // 2788 dwords per buffer (11.2 KB)
#define TU (PAIRS * ROWS * NC4)  // 680 units per group (unit = 4 px x 2 ch)
#define NS 3                     // units per thread (ceil 680/256)

// packed-weight table in d_ws:
//   uint wpk[4][32][9] : half2(w[k][2p][tap], w[k][2p+1][tap])  (1152)
//   uint apk[4][32]    : half2(attn_w[k][2p], attn_w[k][2p+1])  (128)
#define WPK_N 1152
#define APK_OFF 1152

__device__ __forceinline__ uint pkrtz(float a, float b) {
    return __builtin_bit_cast(uint, __builtin_amdgcn_cvt_pkrtz(a, b));
}

__device__ __forceinline__ float dot2(uint a, uint b, float c) {
#if __has_builtin(__builtin_amdgcn_fdot2)
    return __builtin_amdgcn_fdot2(__builtin_bit_cast(half2_t, a),
                                  __builtin_bit_cast(half2_t, b), c, false);
#else
    half2_t ha = __builtin_bit_cast(half2_t, a);
    half2_t hb = __builtin_bit_cast(half2_t, b);
    return c + (float)ha[0] * (float)hb[0] + (float)ha[1] * (float)hb[1];
#endif
}

__global__ void kwdc_pack(const float* __restrict__ weight,
                          const float* __restrict__ attn_w,
                          uint* __restrict__ wsu) {
    int e = blockIdx.x * 256 + threadIdx.x;
    if (e < WPK_N) {
        int k = e / 288, rem = e % 288, pair = rem / 9, tap = rem % 9;
        int c0 = 2 * pair;
        wsu[e] = pkrtz(weight[(k * CH + c0) * 9 + tap],
                       weight[(k * CH + c0 + 1) * 9 + tap]);
    } else if (e < WPK_N + 128) {
        int e2 = e - WPK_N;
        int k = e2 / 32, pair = e2 % 32;
        int c0 = 2 * pair;
        wsu[APK_OFF + e2] = pkrtz(attn_w[k * CH + c0], attn_w[k * CH + c0 + 1]);
    }
}

__global__ __launch_bounds__(256, 4) void kwdc_main(
    const float* __restrict__ x,       // [B,C,H,W] f32
    const uint*  __restrict__ wsu,     // packed weights (d_ws)
    const float* __restrict__ attn_b,  // [K] f32
    float* __restrict__ out)           // [B,1,H,W] f32
{
    __shared__ uint lds[2][BUF_DW];    // 2 x 11.2 KB

    const int tid = threadIdx.x;

    // XCD-aware decode: the 8 tiles of an image row share fid mod 8 -> same XCD
    const int fid = blockIdx.x;        // 0..1023
    const int tw = (fid >> 3) & 7;
    const int th = fid & 7;
    const int b  = fid >> 6;

    const int r  = tid >> 3;     // 0..31 row in tile
    const int cg = tid & 7;      // col group
    const int wb = cg * 4;       // col base (4-wide strip)

    const int h0 = th * TILE;
    const int w0 = tw * TILE;

    const float* xb = x + (size_t)b * CH * PLANE;

    // ---- staging metadata (unit = 4 px of one channel pair) ----
    int  s_ch[NS];      // pair within group (0/1)
    int  s_gofs[NS];
    int  s_lofs[NS];
    bool s_val[NS];
    bool s_act[NS];
#pragma unroll
    for (int s = 0; s < NS; ++s) {
        int i = tid + s * 256;
        bool act = i < TU;
        int col4  = i % NC4;
        int rowch = i / NC4;
        int row   = rowch % ROWS;
        int pr    = rowch / ROWS;         // pair 0/1
        int gh  = h0 + row - 1;
        int gw0 = w0 - 4 + col4 * 4;      // 16B-aligned; fully in or fully out
        s_act[s]  = act;
        s_val[s]  = act && ((unsigned)gh < HH) && ((unsigned)gw0 < WW);
        s_gofs[s] = gh * WW + gw0;
        s_lofs[s] = pr * PSTRIDE + row * LDSS + col4 * 4;
        s_ch[s]   = pr;
    }

    struct Unit { float4 a, b; };
    Unit stgA[NS], stgB[NS];           // 2-deep prefetch sets

    auto load_set = [&](int g, Unit* stg) {
#pragma unroll
        for (int s = 0; s < NS; ++s) {
            float4 va = {0.f, 0.f, 0.f, 0.f}, vb = va;
            if (s_val[s]) {
                const float* pa = xb + (size_t)(g * 4 + s_ch[s] * 2) * PLANE + s_gofs[s];
                va = *reinterpret_cast<const float4*>(pa);
                vb = *reinterpret_cast<const float4*>(pa + PLANE);
            }
            stg[s].a = va; stg[s].b = vb;
        }
    };

    auto store_set = [&](const Unit* stg, int buf) {
#pragma unroll
        for (int s = 0; s < NS; ++s) {
            if (s_act[s]) {
                uint* q = &lds[buf][s_lofs[s]];
                q[0] = pkrtz(stg[s].a.x, stg[s].b.x);
                q[1] = pkrtz(stg[s].a.y, stg[s].b.y);
                q[2] = pkrtz(stg[s].a.z, stg[s].b.z);
                q[3] = pkrtz(stg[s].a.w, stg[s].b.w);
            }
        }
    };

    float conv[4][4];
    float logit[4][4];
#pragma unroll
    for (int k = 0; k < 4; ++k)
#pragma unroll
        for (int p = 0; p < 4; ++p) { conv[k][p] = 0.f; logit[k][p] = 0.f; }

    // ---- prologue: stage group 0; prime 2-deep pipeline ----
    load_set(0, stgA);
    store_set(stgA, 0);
    load_set(1, stgA);   // A holds g1 (stored at iter 0)
    load_set(2, stgB);   // B holds g2 (stored at iter 1)
    __syncthreads();     // buf0 ready

    for (int g = 0; g < NG; ++g) {
        // ---- store set (holds g+1, loaded 2 iters ago); refill with g+3 ----
        if (g + 1 < NG) {
            Unit* setp = (g & 1) ? stgB : stgA;
            store_set(setp, (g + 1) & 1);
            if (g + 3 < NG) load_set(g + 3, setp);
        }

        // ---- compute the 2 pairs (4 channels) of this group ----
#pragma unroll
        for (int pr = 0; pr < PAIRS; ++pr) {
            const int gp = g * PAIRS + pr;       // global pair index 0..31
            const uint* tp = &lds[g & 1][pr * PSTRIDE + r * LDSS + wb + 3];
            uint rv[3][6];
#pragma unroll
            for (int i = 0; i < 3; ++i)
#pragma unroll
                for (int j = 0; j < 6; ++j)
                    rv[i][j] = tp[i * LDSS + j];

#pragma unroll
            for (int k = 0; k < 4; ++k) {
                const uint* wq = wsu + k * 288 + gp * 9;   // uniform -> s_load
                uint w2[9];
#pragma unroll
                for (int t = 0; t < 9; ++t) w2[t] = wq[t];
                const uint a2 = wsu[APK_OFF + k * 32 + gp];
#pragma unroll
                for (int p = 0; p < 4; ++p) {
                    float acc = conv[k][p];
                    acc = dot2(rv[0][p],     w2[0], acc);
                    acc = dot2(rv[0][p + 1], w2[1], acc);
                    acc = dot2(rv[0][p + 2], w2[2], acc);
                    acc = dot2(rv[1][p],     w2[3], acc);
                    acc = dot2(rv[1][p + 1], w2[4], acc);
                    acc = dot2(rv[1][p + 2], w2[5], acc);
                    acc = dot2(rv[2][p],     w2[6], acc);
                    acc = dot2(rv[2][p + 1], w2[7], acc);
                    acc = dot2(rv[2][p + 2], w2[8], acc);
                    conv[k][p] = acc;
                    logit[k][p] = dot2(rv[1][p + 1], a2, logit[k][p]);
                }
            }
        }
        // one barrier per group (16 total): buf[g&1] reads done before iter
        // g+1 rewrites it; buf[(g+1)&1] writes visible next iter
        __syncthreads();
    }

    // ---- epilogue: softmax over K=4 + mixture (all f32) ----
    const float b0 = attn_b[0], b1 = attn_b[1], b2 = attn_b[2], b3 = attn_b[3];
    float4 o;
    float* op = &o.x;
#pragma unroll
    for (int p = 0; p < 4; ++p) {
        float l0 = logit[0][p] + b0;
        float l1 = logit[1][p] + b1;
        float l2 = logit[2][p] + b2;
        float l3 = logit[3][p] + b3;
        float m = fmaxf(fmaxf(l0, l1), fmaxf(l2, l3));
        float e0 = __expf(l0 - m), e1 = __expf(l1 - m);
        float e2 = __expf(l2 - m), e3 = __expf(l3 - m);
        float s = e0 + e1 + e2 + e3;
        float num = conv[0][p] * e0 + conv[1][p] * e1
                  + conv[2][p] * e2 + conv[3][p] * e3;
        op[p] = num / s;
    }
    size_t oidx = (size_t)b * PLANE + (size_t)(h0 + r) * WW + (w0 + wb);
    *reinterpret_cast<float4*>(out + oidx) = o;
}

extern "C" void kernel_launch(void* const* d_in, const int* in_sizes, int n_in,
                              void* d_out, int out_size, void* d_ws, size_t ws_size,
                              hipStream_t stream) {
    const float* x      = (const float*)d_in[0];
    const float* weight = (const float*)d_in[1];
    const float* attn_w = (const float*)d_in[2];
    const float* attn_b = (const float*)d_in[3];
    float* out = (float*)d_out;
    uint*  wsu = (uint*)d_ws;

    kwdc_pack<<<dim3(5), 256, 0, stream>>>(weight, attn_w, wsu);
    kwdc_main<<<dim3(1024), 256, 0, stream>>>(x, wsu, attn_b, out);
}